// Round 10
// baseline (1187.725 us; speedup 1.0000x reference)
//
#include <hip/hip_runtime.h>
#include <cstdint>
#include <cstddef>

// SAGE-LSTM R10: R8 structure, spill fixed.
// Evidence chain: rec throughput ~ 1/(blocks/CU) (R7 2blk=273us, R9 1blk=465us,
// R8 3blk-but-spilled=487us). Latency-bound: FETCH 374MB >> 51MB Xu means the
// random 1KB-row gather misses L2 every step; only wave parallelism hides it.
// Fix vs R8: __launch_bounds__(256) WITHOUT min-waves -> allocator keeps
// W_hh's 128 regs resident (R9 measured 148 VGPR natural need = 3 waves/SIMD);
// LDS 42.5KB allows 3 blocks/CU. Same kernel body as R8 otherwise.

constexpr int IN  = 128;
constexpr int DEG = 16;

typedef short bf16x8 __attribute__((ext_vector_type(8)));
typedef float f32x16 __attribute__((ext_vector_type(16)));
typedef unsigned int u32x4 __attribute__((ext_vector_type(4)));
typedef unsigned int u32x2 __attribute__((ext_vector_type(2)));

__device__ __forceinline__ float fsigmoid(float x) {
    float e = __expf(-x);
    return __builtin_amdgcn_rcpf(1.0f + e);
}
__device__ __forceinline__ float ftanh(float x) {
    float e = __expf(-2.0f * x);
    return __fmaf_rn(2.0f, __builtin_amdgcn_rcpf(1.0f + e), -1.0f);
}
__device__ __forceinline__ uint32_t pack2bf16(float a, float b) {
    uint32_t ua = __float_as_uint(a) + 0x8000u;
    uint32_t ub = __float_as_uint(b) + 0x8000u;
    return (ua >> 16) | (ub & 0xFFFF0000u);
}

// async global->LDS, 16B/lane; LDS base wave-uniform, lands at lds + lane*16.
__device__ __forceinline__ void gld_lds16(const void* gsrc, void* ldst) {
    __builtin_amdgcn_global_load_lds(
        (const __attribute__((address_space(1))) unsigned int*)gsrc,
        (__attribute__((address_space(3))) unsigned int*)ldst,
        16, 0, 0);
}

// ---------- prep kernels (fused) ----------

__global__ void k_transpose_all(const float* __restrict__ s0, float* __restrict__ d0,
                                const float* __restrict__ s1, float* __restrict__ d1,
                                const float* __restrict__ s2, float* __restrict__ d2,
                                const float* __restrict__ s3, float* __restrict__ d3) {
    int i = blockIdx.x * blockDim.x + threadIdx.x;
    if (i < 16384) {
        int r = i >> 7, c = i & 127; d0[c * 128 + r] = s0[i];
    } else if (i < 32768) {
        int j = i - 16384; int r = j >> 7, c = j & 127; d1[c * 128 + r] = s1[j];
    } else if (i < 40960) {
        int j = i - 32768; int r = j >> 7, c = j & 127; d2[c * 64 + r] = s2[j];
    } else if (i < 49152) {
        int j = i - 40960; int r = j >> 7, c = j & 127; d3[c * 64 + r] = s3[j];
    }
}

__global__ void k_cast_bf16(const float* __restrict__ src, ushort* __restrict__ dst, int n) {
    int i = (blockIdx.x * blockDim.x + threadIdx.x) * 4;
    if (i + 3 < n) {
        float4 v = *(const float4*)(src + i);
        uint2 d; d.x = pack2bf16(v.x, v.y); d.y = pack2bf16(v.z, v.w);
        *(uint2*)(dst + i) = d;
    } else {
        for (int k = i; k < n; ++k)
            dst[k] = (ushort)((__float_as_uint(src[k]) + 0x8000u) >> 16);
    }
}

// Pack all 4 [512 x 128] weights into MFMA B-fragment order.
// frag[(kst*16 + tile)*64 + lane]; B[k][n]: n = tile*32+(lane&31),
// k = kst*16 + (lane>>5)*8 + j. tile = g*4 + w.
__global__ void k_pack_all(const float* __restrict__ w0, u32x4* __restrict__ f0,
                           const float* __restrict__ w1, u32x4* __restrict__ f1,
                           const float* __restrict__ w2, u32x4* __restrict__ f2,
                           const float* __restrict__ w3, u32x4* __restrict__ f3) {
    int gt = blockIdx.x * 256 + threadIdx.x;     // 0..32767
    int which = gt >> 13;
    int tid  = gt & 8191;
    const float* wsrc = (which == 0) ? w0 : (which == 1) ? w1 : (which == 2) ? w2 : w3;
    u32x4* frag = (which == 0) ? f0 : (which == 1) ? f1 : (which == 2) ? f2 : f3;
    int lane = tid & 63;
    int tile = (tid >> 6) & 15;
    int kst  = tid >> 10;
    int n     = tile * 32 + (lane & 31);
    int kbase = kst * 16 + (lane >> 5) * 8;
    float v[8];
#pragma unroll
    for (int j = 0; j < 8; ++j) v[j] = wsrc[n * 128 + kbase + j];
    u32x4 d;
    d.x = pack2bf16(v[0], v[1]);
    d.y = pack2bf16(v[2], v[3]);
    d.z = pack2bf16(v[4], v[5]);
    d.w = pack2bf16(v[6], v[7]);
    frag[tid] = d;
}

// ---------- kernel A: Xu = x @ W_ih^T + (b_ih+b_hh), swizzled row store ----------
__global__ __launch_bounds__(256, 2) void k_xu(
    const ushort* __restrict__ x,       // [N,128] bf16
    const u32x4*  __restrict__ wih,     // 8192 B-frags
    const float*  __restrict__ b_ih,    // [512]
    const float*  __restrict__ b_hh,    // [512]
    u32x2*        __restrict__ xu,      // [Nceil][128] u32x2 (1KB rows)
    int N)
{
    __shared__ u32x4 a_buf[16][66];

    const int tid   = threadIdx.x;
    const int lane  = tid & 63;
    const int w     = tid >> 6;
    const int mrow  = lane & 31;
    const int khalf = lane >> 5;
    const int node0 = blockIdx.x * 64;

    u32x4 wreg[8][4];
#pragma unroll
    for (int kst = 0; kst < 8; ++kst)
#pragma unroll
        for (int g = 0; g < 4; ++g)
            wreg[kst][g] = wih[(kst * 16 + g * 4 + w) * 64 + lane];

    float binit[4];
#pragma unroll
    for (int g = 0; g < 4; ++g) {
        int jj = g * 128 + w * 32 + mrow;
        binit[g] = b_ih[jj] + b_hh[jj];
    }

    {
        int m_st = tid >> 2, c4 = tid & 3;
        int gn = node0 + m_st; if (gn >= N) gn = N - 1;
        const u32x4* src = (const u32x4*)(x + (size_t)gn * IN);
#pragma unroll
        for (int q = 0; q < 4; ++q) {
            int kg = q * 4 + c4;
            a_buf[kg][m_st] = src[kg];
        }
    }
    __syncthreads();

    const int coff = w * 32 + mrow;
    // sequential M-tiles: halves live accumulator registers (spill guard)
#pragma unroll 1
    for (int Mt = 0; Mt < 2; ++Mt) {
        f32x16 acc[4];
#pragma unroll
        for (int g = 0; g < 4; ++g)
#pragma unroll
            for (int r = 0; r < 16; ++r) acc[g][r] = binit[g];

#pragma unroll
        for (int kst = 0; kst < 8; ++kst) {
            bf16x8 a = __builtin_bit_cast(bf16x8, a_buf[kst * 2 + khalf][Mt * 32 + mrow]);
#pragma unroll
            for (int g = 0; g < 4; ++g)
                acc[g] = __builtin_amdgcn_mfma_f32_32x32x16_bf16(
                    a, __builtin_bit_cast(bf16x8, wreg[kst][g]), acc[g], 0, 0, 0);
        }

#pragma unroll
        for (int r = 0; r < 16; ++r) {
            int m = Mt * 32 + (r & 3) + 8 * (r >> 2) + 4 * khalf;
            u32x2 d;
            d.x = pack2bf16(acc[0][r], acc[1][r]);
            d.y = pack2bf16(acc[2][r], acc[3][r]);
            xu[(size_t)(node0 + m) * 128 + coff] = d;
        }
    }
}

// ---------- kernel B: recurrent LSTM (single stage buffer, natural regs) ----------
__global__ __launch_bounds__(256) void k_lstm_rec6(
    const u32x2* __restrict__ xu,       // 1KB swizzled rows
    const int*   __restrict__ nbr,      // [N,16]
    const u32x4* __restrict__ whh,      // 8192 B-frags
    ushort*      __restrict__ h_out,    // [N,128] bf16
    int N)
{
    __shared__ u32x4 stage[32][64];      // 32KB single buffer
    __shared__ u32x4 h_frag[16 * 33];    // 8.25KB padded
    __shared__ int   idxs[DEG * 32];     // 2KB [t][m]

    const int tid   = threadIdx.x;
    const int lane  = tid & 63;
    const int w     = tid >> 6;          // wave = gate group 0..3
    const int mrow  = lane & 31;
    const int khalf = lane >> 5;
    const int node0 = blockIdx.x * 32;
    const int coff  = w * 32 + mrow;

    for (int i = tid; i < 32 * DEG; i += 256) {
        int m = i & 31, t = i >> 5;
        int gn = node0 + m; if (gn >= N) gn = N - 1;
        idxs[t * 32 + m] = nbr[gn * DEG + t];
    }
    for (int i = tid; i < 16 * 33; i += 256) h_frag[i] = u32x4{0u, 0u, 0u, 0u};
    __syncthreads();                     // idxs ready for staging

    // prime stage(0): wave w stages rows w*8..w*8+7
#pragma unroll
    for (int r8 = 0; r8 < 8; ++r8) {
        int m = w * 8 + r8;
        int idx = idxs[0 * 32 + m];
        const char* row = (const char*)xu + (size_t)idx * 1024;
        gld_lds16(row + lane * 16, &stage[m][0]);
    }

    // W_hh fragments for my gate group (128 regs); overlaps stage latency
    u32x4 wreg[8][4];
#pragma unroll
    for (int kst = 0; kst < 8; ++kst)
#pragma unroll
        for (int g = 0; g < 4; ++g)
            wreg[kst][g] = whh[(kst * 16 + g * 4 + w) * 64 + lane];

    float cst[16];
#pragma unroll
    for (int r = 0; r < 16; ++r) cst[r] = 0.0f;

    __syncthreads();   // drains stage(0) + wreg vmcnt; h zeros visible

#pragma unroll 2
    for (int t = 0; t < DEG; ++t) {
        // ---- acc init from staged Xu rows (gates i,f,g,o packed as u32x2)
        f32x16 acc[4];
#pragma unroll
        for (int r = 0; r < 16; ++r) {
            int m = (r & 3) + 8 * (r >> 2) + 4 * khalf;
            u32x2 v = ((const u32x2*)&stage[m][0])[coff];
            acc[0][r] = __uint_as_float(v.x << 16);
            acc[1][r] = __uint_as_float(v.x & 0xFFFF0000u);
            acc[2][r] = __uint_as_float(v.y << 16);
            acc[3][r] = __uint_as_float(v.y & 0xFFFF0000u);
        }

        __syncthreads();   // barrier A: all stage reads done; h(t-1) visible

        // ---- issue stage(t+1) into the same buffer: WAR-safe (reads done),
        // drained at barrier B (cover = MFMA + cell update)
        if (t < DEG - 1) {
#pragma unroll
            for (int r8 = 0; r8 < 8; ++r8) {
                int m = w * 8 + r8;
                int idx = idxs[(t + 1) * 32 + m];
                const char* row = (const char*)xu + (size_t)idx * 1024;
                gld_lds16(row + lane * 16, &stage[m][0]);
            }
        }

        // ---- MFMA: A = h(t-1) from LDS, B = wreg
#pragma unroll
        for (int kst = 0; kst < 8; ++kst) {
            bf16x8 a = __builtin_bit_cast(bf16x8, h_frag[(kst * 2 + khalf) * 33 + mrow]);
#pragma unroll
            for (int g = 0; g < 4; ++g)
                acc[g] = __builtin_amdgcn_mfma_f32_32x32x16_bf16(
                    a, __builtin_bit_cast(bf16x8, wreg[kst][g]), acc[g], 0, 0, 0);
        }

        // ---- cell update (registers only)
        float hv16[16];
#pragma unroll
        for (int r = 0; r < 16; ++r) {
            float iv = fsigmoid(acc[0][r]);
            float fv = fsigmoid(acc[1][r]);
            float gv = ftanh(acc[2][r]);
            float ov = fsigmoid(acc[3][r]);
            float cv = __fmaf_rn(fv, cst[r], iv * gv);
            cst[r] = cv;
            hv16[r] = ov * ftanh(cv);
        }

        __syncthreads();   // barrier B: h(t-1) reads done; stage(t+1) drained

        // ---- h(t) write (A-frag layout, padded stride 33)
#pragma unroll
        for (int r = 0; r < 16; ++r) {
            uint32_t hb = __float_as_uint(hv16[r]) + 0x8000u;
            uint32_t pb = (uint32_t)__shfl_xor((int)hb, 1, 64);
            if ((lane & 1) == 0) {
                int row = (r & 3) + 8 * (r >> 2) + 4 * khalf;
                int j   = w * 32 + mrow;
                ((uint32_t*)h_frag)[((j >> 3) * 33 + row) * 4 + ((lane >> 1) & 3)] =
                    (hb >> 16) | (pb & 0xFFFF0000u);
            }
        }
    }

    __syncthreads();
    for (int i = tid; i < 32 * IN; i += 256) {
        int m = i >> 7, j = i & 127;
        int gn = node0 + m;
        if (gn < N)
            h_out[(size_t)gn * IN + j] =
                ((const ushort*)h_frag)[((j >> 3) * 33 + m) * 8 + (j & 7)];
    }
}

// ---------- output linear (fp32 math, bf16 inputs) ----------

template <int NOUT, int ACT, typename OutT>
__global__ __launch_bounds__(256) void k_out_linear(
    const ushort* __restrict__ x, const ushort* __restrict__ h,
    const float* __restrict__ wTs, const float* __restrict__ wTn,
    const float* __restrict__ bias, OutT* __restrict__ out, int N)
{
    constexpr int NPS = 32 / (256 / NOUT);
    __shared__ alignas(16) float x_lds[32][IN];
    __shared__ alignas(16) float h_lds[32][IN];

    const int tid  = threadIdx.x;
    const int j    = tid % NOUT;
    const int slot = tid / NOUT;
    const int node0 = blockIdx.x * 32;

    for (int i = tid; i < 32 * (IN / 8); i += 256) {
        int n = i >> 4, u4 = i & 15;
        int gn = node0 + n; if (gn >= N) gn = N - 1;
        u32x4 xv = *(const u32x4*)(x + (size_t)gn * IN + u4 * 8);
        u32x4 hv = *(const u32x4*)(h + (size_t)gn * IN + u4 * 8);
        float* xd = &x_lds[n][u4 * 8];
        float* hd = &h_lds[n][u4 * 8];
        xd[0] = __uint_as_float(xv.x << 16); xd[1] = __uint_as_float(xv.x & 0xFFFF0000u);
        xd[2] = __uint_as_float(xv.y << 16); xd[3] = __uint_as_float(xv.y & 0xFFFF0000u);
        xd[4] = __uint_as_float(xv.z << 16); xd[5] = __uint_as_float(xv.z & 0xFFFF0000u);
        xd[6] = __uint_as_float(xv.w << 16); xd[7] = __uint_as_float(xv.w & 0xFFFF0000u);
        hd[0] = __uint_as_float(hv.x << 16); hd[1] = __uint_as_float(hv.x & 0xFFFF0000u);
        hd[2] = __uint_as_float(hv.y << 16); hd[3] = __uint_as_float(hv.y & 0xFFFF0000u);
        hd[4] = __uint_as_float(hv.z << 16); hd[5] = __uint_as_float(hv.z & 0xFFFF0000u);
        hd[6] = __uint_as_float(hv.w << 16); hd[7] = __uint_as_float(hv.w & 0xFFFF0000u);
    }
    __syncthreads();

    float acc[NPS];
    const float bj = bias[j];
#pragma unroll
    for (int n = 0; n < NPS; ++n) acc[n] = bj;

#pragma unroll 2
    for (int k = 0; k < IN; ++k) {
        const float ws = wTs[k * NOUT + j];
        const float wn = wTn[k * NOUT + j];
#pragma unroll
        for (int n = 0; n < NPS; ++n) {
            acc[n] = __fmaf_rn(x_lds[slot * NPS + n][k], ws,
                     __fmaf_rn(h_lds[slot * NPS + n][k], wn, acc[n]));
        }
    }

#pragma unroll
    for (int n = 0; n < NPS; ++n) {
        int gn = node0 + slot * NPS + n;
        if (gn < N) {
            float v = acc[n];
            v = (ACT == 0) ? fmaxf(v, 0.0f) : fsigmoid(v);
            if constexpr (sizeof(OutT) == 2)
                out[(size_t)gn * NOUT + j] = (OutT)((__float_as_uint(v) + 0x8000u) >> 16);
            else
                out[(size_t)gn * NOUT + j] = v;
        }
    }
}

extern "C" void kernel_launch(void* const* d_in, const int* in_sizes, int n_in,
                              void* d_out, int out_size, void* d_ws, size_t ws_size,
                              hipStream_t stream)
{
    const float* feats    = (const float*)d_in[0];
    const int*   nbr      = (const int*)  d_in[1];
    const float* w_ih1    = (const float*)d_in[2];
    const float* w_hh1    = (const float*)d_in[3];
    const float* b_ih1    = (const float*)d_in[4];
    const float* b_hh1    = (const float*)d_in[5];
    const float* w_self1  = (const float*)d_in[6];
    const float* w_neigh1 = (const float*)d_in[7];
    const float* b1       = (const float*)d_in[8];
    const float* w_ih2    = (const float*)d_in[9];
    const float* w_hh2    = (const float*)d_in[10];
    const float* b_ih2    = (const float*)d_in[11];
    const float* b_hh2    = (const float*)d_in[12];
    const float* w_self2  = (const float*)d_in[13];
    const float* w_neigh2 = (const float*)d_in[14];
    const float* b2       = (const float*)d_in[15];
    float* out = (float*)d_out;

    const int N = in_sizes[0] / IN;   // 50000
    const long long Nceil = (N + 63) & ~63LL;

    char* ws = (char*)d_ws;
    size_t off = 0;
    auto alloc = [&](size_t bytes) -> void* {
        void* p = (void*)(ws + off);
        off += (bytes + 255) & ~(size_t)255;
        return p;
    };
    u32x4*  wfrag_ih1 = (u32x4*)alloc(8192 * 16);
    u32x4*  wfrag_hh1 = (u32x4*)alloc(8192 * 16);
    u32x4*  wfrag_ih2 = (u32x4*)alloc(8192 * 16);
    u32x4*  wfrag_hh2 = (u32x4*)alloc(8192 * 16);
    float*  wT_self1  = (float*)alloc(128 * 128 * 4);
    float*  wT_neigh1 = (float*)alloc(128 * 128 * 4);
    float*  wT_self2  = (float*)alloc(64 * 128 * 4);
    float*  wT_neigh2 = (float*)alloc(64 * 128 * 4);
    ushort* feats_bf  = (ushort*)alloc((size_t)N * 128 * 2);
    ushort* h_buf     = (ushort*)alloc((size_t)N * 128 * 2);
    ushort* out1      = (ushort*)alloc((size_t)N * 128 * 2);
    u32x2*  xu_buf    = (u32x2*)alloc((size_t)Nceil * 128 * 8);   // 51.25MB

    // prep (fused)
    k_pack_all<<<dim3(128), dim3(256), 0, stream>>>(w_ih1, wfrag_ih1, w_hh1, wfrag_hh1,
                                                    w_ih2, wfrag_ih2, w_hh2, wfrag_hh2);
    k_transpose_all<<<dim3(192), dim3(256), 0, stream>>>(w_self1, wT_self1, w_neigh1, wT_neigh1,
                                                         w_self2, wT_self2, w_neigh2, wT_neigh2);
    k_cast_bf16<<<dim3((N * 128 / 4 + 255) / 256), dim3(256), 0, stream>>>(feats, feats_bf, N * 128);

    const int nblk64 = (int)(Nceil / 64);
    const int nblk32 = (N + 31) / 32;

    // layer 1
    k_xu<<<dim3(nblk64), dim3(256), 0, stream>>>(feats_bf, wfrag_ih1, b_ih1, b_hh1, xu_buf, N);
    k_lstm_rec6<<<dim3(nblk32), dim3(256), 0, stream>>>(xu_buf, nbr, wfrag_hh1, h_buf, N);
    k_out_linear<128, 0, ushort><<<dim3(nblk32), dim3(256), 0, stream>>>(feats_bf, h_buf, wT_self1, wT_neigh1, b1, out1, N);

    // layer 2
    k_xu<<<dim3(nblk64), dim3(256), 0, stream>>>(out1, wfrag_ih2, b_ih2, b_hh2, xu_buf, N);
    k_lstm_rec6<<<dim3(nblk32), dim3(256), 0, stream>>>(xu_buf, nbr, wfrag_hh2, h_buf, N);
    k_out_linear<64, 1, float><<<dim3(nblk32), dim3(256), 0, stream>>>(out1, h_buf, wT_self2, wT_neigh2, b2, out, N);
}

// Round 11
// 793.195 us; speedup vs baseline: 1.4974x; 1.4974x over previous
//
#include <hip/hip_runtime.h>
#include <cstdint>
#include <cstddef>

// SAGE-LSTM R11: R7 resource shape + pair-staging.
// Resolved occupancy model (R7-R10): limiter is TOTAL regs (VGPR+AGPR
// unified; waves/SIMD halves at 64/128/256/wave). wreg(128 AGPR)+acc(64)+misc:
// natural alloc = 148 VGPR -> 276 total -> 1 wave/SIMD (R9/R10, 466us);
// launch_bounds(256,2) -> 124 VGPR -> 252 total -> 2 waves/SIMD (R7, 273us);
// (256,3) -> forced spill (R8, 487us). So (256,2) is mandatory, 8 waves/CU is
// the ceiling, and LDS below ~75KB buys nothing.
// New: stage TWO steps per gather round (one 64KB buffer = pair {t,t+1}).
// Even steps issue no loads -> their barrier drains nothing (no stall);
// odd steps issue 16 loads for the next pair -> one vmcnt drain per 2 steps
// instead of per step. Same bytes, half the stall events.

constexpr int IN  = 128;
constexpr int DEG = 16;

typedef short bf16x8 __attribute__((ext_vector_type(8)));
typedef float f32x16 __attribute__((ext_vector_type(16)));
typedef unsigned int u32x4 __attribute__((ext_vector_type(4)));
typedef unsigned int u32x2 __attribute__((ext_vector_type(2)));

__device__ __forceinline__ float fsigmoid(float x) {
    float e = __expf(-x);
    return __builtin_amdgcn_rcpf(1.0f + e);
}
__device__ __forceinline__ float ftanh(float x) {
    float e = __expf(-2.0f * x);
    return __fmaf_rn(2.0f, __builtin_amdgcn_rcpf(1.0f + e), -1.0f);
}
__device__ __forceinline__ uint32_t pack2bf16(float a, float b) {
    uint32_t ua = __float_as_uint(a) + 0x8000u;
    uint32_t ub = __float_as_uint(b) + 0x8000u;
    return (ua >> 16) | (ub & 0xFFFF0000u);
}

// async global->LDS, 16B/lane; LDS base wave-uniform, lands at lds + lane*16.
__device__ __forceinline__ void gld_lds16(const void* gsrc, void* ldst) {
    __builtin_amdgcn_global_load_lds(
        (const __attribute__((address_space(1))) unsigned int*)gsrc,
        (__attribute__((address_space(3))) unsigned int*)ldst,
        16, 0, 0);
}

// ---------- prep kernels (fused) ----------

__global__ void k_transpose_all(const float* __restrict__ s0, float* __restrict__ d0,
                                const float* __restrict__ s1, float* __restrict__ d1,
                                const float* __restrict__ s2, float* __restrict__ d2,
                                const float* __restrict__ s3, float* __restrict__ d3) {
    int i = blockIdx.x * blockDim.x + threadIdx.x;
    if (i < 16384) {
        int r = i >> 7, c = i & 127; d0[c * 128 + r] = s0[i];
    } else if (i < 32768) {
        int j = i - 16384; int r = j >> 7, c = j & 127; d1[c * 128 + r] = s1[j];
    } else if (i < 40960) {
        int j = i - 32768; int r = j >> 7, c = j & 127; d2[c * 64 + r] = s2[j];
    } else if (i < 49152) {
        int j = i - 40960; int r = j >> 7, c = j & 127; d3[c * 64 + r] = s3[j];
    }
}

__global__ void k_cast_bf16(const float* __restrict__ src, ushort* __restrict__ dst, int n) {
    int i = (blockIdx.x * blockDim.x + threadIdx.x) * 4;
    if (i + 3 < n) {
        float4 v = *(const float4*)(src + i);
        uint2 d; d.x = pack2bf16(v.x, v.y); d.y = pack2bf16(v.z, v.w);
        *(uint2*)(dst + i) = d;
    } else {
        for (int k = i; k < n; ++k)
            dst[k] = (ushort)((__float_as_uint(src[k]) + 0x8000u) >> 16);
    }
}

// Pack all 4 [512 x 128] weights into MFMA B-fragment order.
// frag[(kst*16 + tile)*64 + lane]; B[k][n]: n = tile*32+(lane&31),
// k = kst*16 + (lane>>5)*8 + j. tile = g*4 + w.
__global__ void k_pack_all(const float* __restrict__ w0, u32x4* __restrict__ f0,
                           const float* __restrict__ w1, u32x4* __restrict__ f1,
                           const float* __restrict__ w2, u32x4* __restrict__ f2,
                           const float* __restrict__ w3, u32x4* __restrict__ f3) {
    int gt = blockIdx.x * 256 + threadIdx.x;     // 0..32767
    int which = gt >> 13;
    int tid  = gt & 8191;
    const float* wsrc = (which == 0) ? w0 : (which == 1) ? w1 : (which == 2) ? w2 : w3;
    u32x4* frag = (which == 0) ? f0 : (which == 1) ? f1 : (which == 2) ? f2 : f3;
    int lane = tid & 63;
    int tile = (tid >> 6) & 15;
    int kst  = tid >> 10;
    int n     = tile * 32 + (lane & 31);
    int kbase = kst * 16 + (lane >> 5) * 8;
    float v[8];
#pragma unroll
    for (int j = 0; j < 8; ++j) v[j] = wsrc[n * 128 + kbase + j];
    u32x4 d;
    d.x = pack2bf16(v[0], v[1]);
    d.y = pack2bf16(v[2], v[3]);
    d.z = pack2bf16(v[4], v[5]);
    d.w = pack2bf16(v[6], v[7]);
    frag[tid] = d;
}

// ---------- kernel A: Xu = x @ W_ih^T + (b_ih+b_hh), swizzled row store ----------
__global__ __launch_bounds__(256, 2) void k_xu(
    const ushort* __restrict__ x,       // [N,128] bf16
    const u32x4*  __restrict__ wih,     // 8192 B-frags
    const float*  __restrict__ b_ih,    // [512]
    const float*  __restrict__ b_hh,    // [512]
    u32x2*        __restrict__ xu,      // [Nceil][128] u32x2 (1KB rows)
    int N)
{
    __shared__ u32x4 a_buf[16][66];

    const int tid   = threadIdx.x;
    const int lane  = tid & 63;
    const int w     = tid >> 6;
    const int mrow  = lane & 31;
    const int khalf = lane >> 5;
    const int node0 = blockIdx.x * 64;

    u32x4 wreg[8][4];
#pragma unroll
    for (int kst = 0; kst < 8; ++kst)
#pragma unroll
        for (int g = 0; g < 4; ++g)
            wreg[kst][g] = wih[(kst * 16 + g * 4 + w) * 64 + lane];

    float binit[4];
#pragma unroll
    for (int g = 0; g < 4; ++g) {
        int jj = g * 128 + w * 32 + mrow;
        binit[g] = b_ih[jj] + b_hh[jj];
    }

    {
        int m_st = tid >> 2, c4 = tid & 3;
        int gn = node0 + m_st; if (gn >= N) gn = N - 1;
        const u32x4* src = (const u32x4*)(x + (size_t)gn * IN);
#pragma unroll
        for (int q = 0; q < 4; ++q) {
            int kg = q * 4 + c4;
            a_buf[kg][m_st] = src[kg];
        }
    }
    __syncthreads();

    const int coff = w * 32 + mrow;
    // sequential M-tiles: halves live accumulator registers (spill guard)
#pragma unroll 1
    for (int Mt = 0; Mt < 2; ++Mt) {
        f32x16 acc[4];
#pragma unroll
        for (int g = 0; g < 4; ++g)
#pragma unroll
            for (int r = 0; r < 16; ++r) acc[g][r] = binit[g];

#pragma unroll
        for (int kst = 0; kst < 8; ++kst) {
            bf16x8 a = __builtin_bit_cast(bf16x8, a_buf[kst * 2 + khalf][Mt * 32 + mrow]);
#pragma unroll
            for (int g = 0; g < 4; ++g)
                acc[g] = __builtin_amdgcn_mfma_f32_32x32x16_bf16(
                    a, __builtin_bit_cast(bf16x8, wreg[kst][g]), acc[g], 0, 0, 0);
        }

#pragma unroll
        for (int r = 0; r < 16; ++r) {
            int m = Mt * 32 + (r & 3) + 8 * (r >> 2) + 4 * khalf;
            u32x2 d;
            d.x = pack2bf16(acc[0][r], acc[1][r]);
            d.y = pack2bf16(acc[2][r], acc[3][r]);
            xu[(size_t)(node0 + m) * 128 + coff] = d;
        }
    }
}

// ---------- kernel B: recurrent LSTM, pair-staged gather ----------
__global__ __launch_bounds__(256, 2) void k_lstm_rec7(
    const u32x2* __restrict__ xu,       // 1KB swizzled rows
    const int*   __restrict__ nbr,      // [N,16]
    const u32x4* __restrict__ whh,      // 8192 B-frags
    ushort*      __restrict__ h_out,    // [N,128] bf16
    int N)
{
    __shared__ u32x4 stage[2][32][64];   // 64KB: [step-in-pair][row][16B chunk]
    __shared__ u32x4 h_frag[16 * 33];    // 8.25KB padded
    __shared__ int   idxs[DEG * 32];     // 2KB [t][m]

    const int tid   = threadIdx.x;
    const int lane  = tid & 63;
    const int w     = tid >> 6;          // wave = gate group 0..3
    const int mrow  = lane & 31;
    const int khalf = lane >> 5;
    const int node0 = blockIdx.x * 32;
    const int coff  = w * 32 + mrow;

    for (int i = tid; i < 32 * DEG; i += 256) {
        int m = i & 31, t = i >> 5;
        int gn = node0 + m; if (gn >= N) gn = N - 1;
        idxs[t * 32 + m] = nbr[gn * DEG + t];
    }
    for (int i = tid; i < 16 * 33; i += 256) h_frag[i] = u32x4{0u, 0u, 0u, 0u};
    __syncthreads();                     // idxs ready for staging

    // prime pair {0,1}: wave w stages rows w*8..w*8+7 for both steps
#pragma unroll
    for (int s = 0; s < 2; ++s)
#pragma unroll
        for (int r8 = 0; r8 < 8; ++r8) {
            int m = w * 8 + r8;
            const char* row = (const char*)xu + (size_t)idxs[s * 32 + m] * 1024;
            gld_lds16(row + lane * 16, &stage[s][m][0]);
        }

    // W_hh fragments for my gate group (128 regs, AGPR-side of unified file)
    u32x4 wreg[8][4];
#pragma unroll
    for (int kst = 0; kst < 8; ++kst)
#pragma unroll
        for (int g = 0; g < 4; ++g)
            wreg[kst][g] = whh[(kst * 16 + g * 4 + w) * 64 + lane];

    float cst[16];
#pragma unroll
    for (int r = 0; r < 16; ++r) cst[r] = 0.0f;

    __syncthreads();   // drains primed stage + wreg; h zeros visible

    // one LSTM step; slot = t&1; loads for the NEXT pair are issued only in
    // slot-1 segments (so slot-0 barriers drain nothing -> no stall).
    auto step = [&](int t, int slot, bool issue) {
        // ---- acc init from stage[slot]
        f32x16 acc[4];
#pragma unroll
        for (int r = 0; r < 16; ++r) {
            int m = (r & 3) + 8 * (r >> 2) + 4 * khalf;
            u32x2 v = ((const u32x2*)&stage[slot][m][0])[coff];
            acc[0][r] = __uint_as_float(v.x << 16);
            acc[1][r] = __uint_as_float(v.x & 0xFFFF0000u);
            acc[2][r] = __uint_as_float(v.y << 16);
            acc[3][r] = __uint_as_float(v.y & 0xFFFF0000u);
        }

        __syncthreads();   // barrier A: stage reads done; h(t-1) writes visible

        // ---- slot-1 only: stage the next pair {t+1, t+2} into both slots.
        // WAR-safe: slot1 read above, slot0 read one step ago (two barriers).
        if (issue) {
#pragma unroll
            for (int s = 0; s < 2; ++s)
#pragma unroll
                for (int r8 = 0; r8 < 8; ++r8) {
                    int m = w * 8 + r8;
                    const char* row = (const char*)xu +
                        (size_t)idxs[(t + 1 + s) * 32 + m] * 1024;
                    gld_lds16(row + lane * 16, &stage[s][m][0]);
                }
        }

        // ---- MFMA: A = h(t-1) from LDS, B = wreg
#pragma unroll
        for (int kst = 0; kst < 8; ++kst) {
            bf16x8 a = __builtin_bit_cast(bf16x8, h_frag[(kst * 2 + khalf) * 33 + mrow]);
#pragma unroll
            for (int g = 0; g < 4; ++g)
                acc[g] = __builtin_amdgcn_mfma_f32_32x32x16_bf16(
                    a, __builtin_bit_cast(bf16x8, wreg[kst][g]), acc[g], 0, 0, 0);
        }

        // ---- cell update (registers only)
        float hv16[16];
#pragma unroll
        for (int r = 0; r < 16; ++r) {
            float iv = fsigmoid(acc[0][r]);
            float fv = fsigmoid(acc[1][r]);
            float gv = ftanh(acc[2][r]);
            float ov = fsigmoid(acc[3][r]);
            float cv = __fmaf_rn(fv, cst[r], iv * gv);
            cst[r] = cv;
            hv16[r] = ov * ftanh(cv);
        }

        __syncthreads();   // barrier B: h reads done; drains loads (slot-1 only)

        // ---- h(t) write (A-frag layout, padded stride 33)
#pragma unroll
        for (int r = 0; r < 16; ++r) {
            uint32_t hb = __float_as_uint(hv16[r]) + 0x8000u;
            uint32_t pb = (uint32_t)__shfl_xor((int)hb, 1, 64);
            if ((lane & 1) == 0) {
                int row = (r & 3) + 8 * (r >> 2) + 4 * khalf;
                int j   = w * 32 + mrow;
                ((uint32_t*)h_frag)[((j >> 3) * 33 + row) * 4 + ((lane >> 1) & 3)] =
                    (hb >> 16) | (pb & 0xFFFF0000u);
            }
        }
    };

#pragma unroll 1
    for (int tt = 0; tt < 8; ++tt) {
        step(2 * tt,     0, false);
        step(2 * tt + 1, 1, tt < 7);
    }

    __syncthreads();
    for (int i = tid; i < 32 * IN; i += 256) {
        int m = i >> 7, j = i & 127;
        int gn = node0 + m;
        if (gn < N)
            h_out[(size_t)gn * IN + j] =
                ((const ushort*)h_frag)[((j >> 3) * 33 + m) * 8 + (j & 7)];
    }
}

// ---------- output linear (fp32 math, bf16 inputs) ----------

template <int NOUT, int ACT, typename OutT>
__global__ __launch_bounds__(256) void k_out_linear(
    const ushort* __restrict__ x, const ushort* __restrict__ h,
    const float* __restrict__ wTs, const float* __restrict__ wTn,
    const float* __restrict__ bias, OutT* __restrict__ out, int N)
{
    constexpr int NPS = 32 / (256 / NOUT);
    __shared__ alignas(16) float x_lds[32][IN];
    __shared__ alignas(16) float h_lds[32][IN];

    const int tid  = threadIdx.x;
    const int j    = tid % NOUT;
    const int slot = tid / NOUT;
    const int node0 = blockIdx.x * 32;

    for (int i = tid; i < 32 * (IN / 8); i += 256) {
        int n = i >> 4, u4 = i & 15;
        int gn = node0 + n; if (gn >= N) gn = N - 1;
        u32x4 xv = *(const u32x4*)(x + (size_t)gn * IN + u4 * 8);
        u32x4 hv = *(const u32x4*)(h + (size_t)gn * IN + u4 * 8);
        float* xd = &x_lds[n][u4 * 8];
        float* hd = &h_lds[n][u4 * 8];
        xd[0] = __uint_as_float(xv.x << 16); xd[1] = __uint_as_float(xv.x & 0xFFFF0000u);
        xd[2] = __uint_as_float(xv.y << 16); xd[3] = __uint_as_float(xv.y & 0xFFFF0000u);
        xd[4] = __uint_as_float(xv.z << 16); xd[5] = __uint_as_float(xv.z & 0xFFFF0000u);
        xd[6] = __uint_as_float(xv.w << 16); xd[7] = __uint_as_float(xv.w & 0xFFFF0000u);
        hd[0] = __uint_as_float(hv.x << 16); hd[1] = __uint_as_float(hv.x & 0xFFFF0000u);
        hd[2] = __uint_as_float(hv.y << 16); hd[3] = __uint_as_float(hv.y & 0xFFFF0000u);
        hd[4] = __uint_as_float(hv.z << 16); hd[5] = __uint_as_float(hv.z & 0xFFFF0000u);
        hd[6] = __uint_as_float(hv.w << 16); hd[7] = __uint_as_float(hv.w & 0xFFFF0000u);
    }
    __syncthreads();

    float acc[NPS];
    const float bj = bias[j];
#pragma unroll
    for (int n = 0; n < NPS; ++n) acc[n] = bj;

#pragma unroll 2
    for (int k = 0; k < IN; ++k) {
        const float ws = wTs[k * NOUT + j];
        const float wn = wTn[k * NOUT + j];
#pragma unroll
        for (int n = 0; n < NPS; ++n) {
            acc[n] = __fmaf_rn(x_lds[slot * NPS + n][k], ws,
                     __fmaf_rn(h_lds[slot * NPS + n][k], wn, acc[n]));
        }
    }

#pragma unroll
    for (int n = 0; n < NPS; ++n) {
        int gn = node0 + slot * NPS + n;
        if (gn < N) {
            float v = acc[n];
            v = (ACT == 0) ? fmaxf(v, 0.0f) : fsigmoid(v);
            if constexpr (sizeof(OutT) == 2)
                out[(size_t)gn * NOUT + j] = (OutT)((__float_as_uint(v) + 0x8000u) >> 16);
            else
                out[(size_t)gn * NOUT + j] = v;
        }
    }
}

extern "C" void kernel_launch(void* const* d_in, const int* in_sizes, int n_in,
                              void* d_out, int out_size, void* d_ws, size_t ws_size,
                              hipStream_t stream)
{
    const float* feats    = (const float*)d_in[0];
    const int*   nbr      = (const int*)  d_in[1];
    const float* w_ih1    = (const float*)d_in[2];
    const float* w_hh1    = (const float*)d_in[3];
    const float* b_ih1    = (const float*)d_in[4];
    const float* b_hh1    = (const float*)d_in[5];
    const float* w_self1  = (const float*)d_in[6];
    const float* w_neigh1 = (const float*)d_in[7];
    const float* b1       = (const float*)d_in[8];
    const float* w_ih2    = (const float*)d_in[9];
    const float* w_hh2    = (const float*)d_in[10];
    const float* b_ih2    = (const float*)d_in[11];
    const float* b_hh2    = (const float*)d_in[12];
    const float* w_self2  = (const float*)d_in[13];
    const float* w_neigh2 = (const float*)d_in[14];
    const float* b2       = (const float*)d_in[15];
    float* out = (float*)d_out;

    const int N = in_sizes[0] / IN;   // 50000
    const long long Nceil = (N + 63) & ~63LL;

    char* ws = (char*)d_ws;
    size_t off = 0;
    auto alloc = [&](size_t bytes) -> void* {
        void* p = (void*)(ws + off);
        off += (bytes + 255) & ~(size_t)255;
        return p;
    };
    u32x4*  wfrag_ih1 = (u32x4*)alloc(8192 * 16);
    u32x4*  wfrag_hh1 = (u32x4*)alloc(8192 * 16);
    u32x4*  wfrag_ih2 = (u32x4*)alloc(8192 * 16);
    u32x4*  wfrag_hh2 = (u32x4*)alloc(8192 * 16);
    float*  wT_self1  = (float*)alloc(128 * 128 * 4);
    float*  wT_neigh1 = (float*)alloc(128 * 128 * 4);
    float*  wT_self2  = (float*)alloc(64 * 128 * 4);
    float*  wT_neigh2 = (float*)alloc(64 * 128 * 4);
    ushort* feats_bf  = (ushort*)alloc((size_t)N * 128 * 2);
    ushort* h_buf     = (ushort*)alloc((size_t)N * 128 * 2);
    ushort* out1      = (ushort*)alloc((size_t)N * 128 * 2);
    u32x2*  xu_buf    = (u32x2*)alloc((size_t)Nceil * 128 * 8);   // 51.25MB

    // prep (fused)
    k_pack_all<<<dim3(128), dim3(256), 0, stream>>>(w_ih1, wfrag_ih1, w_hh1, wfrag_hh1,
                                                    w_ih2, wfrag_ih2, w_hh2, wfrag_hh2);
    k_transpose_all<<<dim3(192), dim3(256), 0, stream>>>(w_self1, wT_self1, w_neigh1, wT_neigh1,
                                                         w_self2, wT_self2, w_neigh2, wT_neigh2);
    k_cast_bf16<<<dim3((N * 128 / 4 + 255) / 256), dim3(256), 0, stream>>>(feats, feats_bf, N * 128);

    const int nblk64 = (int)(Nceil / 64);
    const int nblk32 = (N + 31) / 32;

    // layer 1
    k_xu<<<dim3(nblk64), dim3(256), 0, stream>>>(feats_bf, wfrag_ih1, b_ih1, b_hh1, xu_buf, N);
    k_lstm_rec7<<<dim3(nblk32), dim3(256), 0, stream>>>(xu_buf, nbr, wfrag_hh1, h_buf, N);
    k_out_linear<128, 0, ushort><<<dim3(nblk32), dim3(256), 0, stream>>>(feats_bf, h_buf, wT_self1, wT_neigh1, b1, out1, N);

    // layer 2
    k_xu<<<dim3(nblk64), dim3(256), 0, stream>>>(out1, wfrag_ih2, b_ih2, b_hh2, xu_buf, N);
    k_lstm_rec7<<<dim3(nblk32), dim3(256), 0, stream>>>(xu_buf, nbr, wfrag_hh2, h_buf, N);
    k_out_linear<64, 1, float><<<dim3(nblk32), dim3(256), 0, stream>>>(out1, h_buf, wT_self2, wT_neigh2, b2, out, N);
}